// Round 2
// baseline (748.193 us; speedup 1.0000x reference)
//
#include <hip/hip_runtime.h>

#define BN_EPS 1e-5

// ---------------- adder conv 3x3 pad1, split-K partial, atomic accumulate ----------------
// block: 256 threads = 16 pixel-threads (tx) x 16 o-threads (ty); each thread: 8 o x TP pixels
template<int TP>
__global__ __launch_bounds__(256) void adder_partial(
    const float* __restrict__ x, const float* __restrict__ w,
    float* __restrict__ T, int C, int H, int W, int O, int cpr)
{
    constexpr int KC = 4;
    __shared__ float w_s[KC * 9][128];
    const int tid = threadIdx.x;
    const int tx = tid & 15, ty = tid >> 4;
    const int o_blk = blockIdx.y * 128;
    const int o0 = o_blk + ty * 8;
    const int tpr = W / TP;            // tiles per row (exact for all layer sizes)
    const int PT = 2 * H * tpr;        // B=2
    const int pt = blockIdx.x * 16 + tx;
    const bool act = pt < PT;
    int b = 0, y = 0, x0 = 0;
    if (act) { int t = pt; x0 = (t % tpr) * TP; t /= tpr; y = t % H; b = t / H; }
    const int c0 = blockIdx.z * cpr;
    const int c1 = c0 + cpr;

    bool rv[3]; int yoff[3];
#pragma unroll
    for (int dy = 0; dy < 3; ++dy) {
        int yy = y + dy - 1;
        bool v = act && (yy >= 0) && (yy < H);
        rv[dy] = v; yoff[dy] = (v ? yy : 0) * W;
    }
    const bool lok = (x0 > 0), rok = (x0 + TP) < W;
    const int off0 = lok ? -1 : 0;
    const int offT = rok ? TP : (TP - 1);

    float acc[8][TP];
#pragma unroll
    for (int i = 0; i < 8; i++)
#pragma unroll
        for (int p = 0; p < TP; p++) acc[i][p] = 0.f;

    for (int cs = c0; cs < c1; cs += KC) {
        const int kc = min(KC, c1 - cs);
        const int nk = kc * 9;
        __syncthreads();
        for (int idx = tid; idx < nk * 128; idx += 256) {
            int k = idx >> 7, oo = idx & 127;
            int o = o_blk + oo;
            int c9 = k / 9;
            w_s[k][oo] = (o < O) ? w[((size_t)o * C + (cs + c9)) * 9 + (k - c9 * 9)] : 0.f;
        }
        __syncthreads();
        for (int cc = 0; cc < kc; ++cc) {
            const float* xc = x + ((size_t)(b * C + cs + cc)) * H * W;
#pragma unroll
            for (int dy = 0; dy < 3; ++dy) {
                const float* rp = xc + yoff[dy] + x0;
                float xr[TP + 2];
                { float v = rp[off0]; xr[0] = (rv[dy] && lok) ? v : 0.f; }
#pragma unroll
                for (int j = 1; j <= TP; j++) { float v = rp[j - 1]; xr[j] = rv[dy] ? v : 0.f; }
                { float v = rp[offT]; xr[TP + 1] = (rv[dy] && rok) ? v : 0.f; }
#pragma unroll
                for (int dx = 0; dx < 3; ++dx) {
                    const float4* wp = (const float4*)&w_s[cc * 9 + dy * 3 + dx][ty * 8];
                    float4 wa = wp[0], wb = wp[1];
                    float wv[8] = {wa.x, wa.y, wa.z, wa.w, wb.x, wb.y, wb.z, wb.w};
#pragma unroll
                    for (int i = 0; i < 8; i++)
#pragma unroll
                        for (int p = 0; p < TP; p++)
                            acc[i][p] += fabsf(xr[p + dx] - wv[i]);
                }
            }
        }
    }
    if (act) {
#pragma unroll
        for (int i = 0; i < 8; i++) {
            int o = o0 + i;
            if (o < O) {
                float* Tp = T + ((size_t)(b * O + o) * H + y) * W + x0;
#pragma unroll
                for (int p = 0; p < TP; p++) unsafeAtomicAdd(&Tp[p], -acc[i][p]);
            }
        }
    }
}

// ---------------- BN stats: one block per channel, double accumulators ----------------
__global__ __launch_bounds__(256) void bn_stats(
    const float* __restrict__ T, const float* __restrict__ g, const float* __restrict__ beta,
    float* __restrict__ scale, float* __restrict__ shift, int C, int HW)
{
    __shared__ double s1[256];
    __shared__ double s2[256];
    const int c = blockIdx.x;
    double a = 0.0, q = 0.0;
    for (int idx = threadIdx.x; idx < 2 * HW; idx += 256) {
        int b = idx / HW, i = idx - b * HW;
        float v = T[((size_t)b * C + c) * HW + i];
        a += v; q += (double)v * (double)v;
    }
    s1[threadIdx.x] = a; s2[threadIdx.x] = q;
    __syncthreads();
    for (int s = 128; s > 0; s >>= 1) {
        if (threadIdx.x < s) { s1[threadIdx.x] += s1[threadIdx.x + s]; s2[threadIdx.x] += s2[threadIdx.x + s]; }
        __syncthreads();
    }
    if (threadIdx.x == 0) {
        double n = 2.0 * (double)HW;
        double mu = s1[0] / n;
        double var = s2[0] / n - mu * mu;
        double iv = 1.0 / sqrt(var + (double)BN_EPS);
        double gc = (double)g[c];
        scale[c] = (float)(gc * iv);
        shift[c] = (float)((double)beta[c] - mu * gc * iv);
    }
}

// ---------------- BN apply + feature write + maxpool2 + relu + re-zero T ----------------
__global__ __launch_bounds__(256) void bn_apply_pool(
    float* __restrict__ T, const float* __restrict__ scale, const float* __restrict__ shift,
    float* __restrict__ feat, float* __restrict__ A, int C, int H, int W, int total)
{
    int idx = blockIdx.x * 256 + threadIdx.x;
    if (idx >= total) return;
    int Wh = W >> 1, Hh = H >> 1;
    int px = idx % Wh; int t = idx / Wh;
    int py = t % Hh; t /= Hh;
    int c = t % C; int b = t / C;
    size_t base = ((size_t)(b * C + c) * H + 2 * py) * W + 2 * px;
    float sc = scale[c], sh = shift[c];
    float f0 = T[base] * sc + sh;
    float f1 = T[base + 1] * sc + sh;
    float f2 = T[base + W] * sc + sh;
    float f3 = T[base + W + 1] * sc + sh;
    feat[base] = f0; feat[base + 1] = f1; feat[base + W] = f2; feat[base + W + 1] = f3;
    T[base] = 0.f; T[base + 1] = 0.f; T[base + W] = 0.f; T[base + W + 1] = 0.f;
    A[((size_t)(b * C + c) * Hh + py) * Wh + px] = fmaxf(fmaxf(fmaxf(f0, f1), fmaxf(f2, f3)), 0.f);
}

__global__ __launch_bounds__(256) void bn_apply_np(
    float* __restrict__ T, const float* __restrict__ scale, const float* __restrict__ shift,
    float* __restrict__ feat, float* __restrict__ A, int C, int HW, int total)
{
    int idx = blockIdx.x * 256 + threadIdx.x;
    if (idx >= total) return;
    int c = (idx / HW) % C;
    float f = T[idx] * scale[c] + shift[c];
    feat[idx] = f;
    A[idx] = fmaxf(f, 0.f);
    T[idx] = 0.f;
}

// ---------------- global max over 3x3 ----------------
__global__ __launch_bounds__(256) void gmax9(const float* __restrict__ A, float* __restrict__ xp)
{
    int idx = blockIdx.x * 256 + threadIdx.x;
    if (idx >= 1024) return;
    const float* p = A + (size_t)idx * 9;
    float m = p[0];
#pragma unroll
    for (int i = 1; i < 9; i++) m = fmaxf(m, p[i]);
    xp[idx] = m;
}

// ---------------- final 1x1 adder "linear": fo[b][o] = -sum_c |xp[b,c]-wl[o,c]| ----------------
__global__ __launch_bounds__(256) void final_adder(
    const float* __restrict__ xp, const float* __restrict__ wl, float* __restrict__ fo)
{
    __shared__ float xs[1024];
    for (int i = threadIdx.x; i < 1024; i += 256) xs[i] = xp[i];
    __syncthreads();
    int o = blockIdx.x * 128 + (threadIdx.x >> 1);
    int b = threadIdx.x & 1;
    if (o >= 1000) return;
    const float* wrow = wl + (size_t)o * 512;
    const float* xb = xs + b * 512;
    double s = 0.0;
    for (int c = 0; c < 512; c += 4) {
        float4 wv = *(const float4*)&wrow[c];
        s += (double)fabsf(xb[c] - wv.x) + (double)fabsf(xb[c + 1] - wv.y)
           + (double)fabsf(xb[c + 2] - wv.z) + (double)fabsf(xb[c + 3] - wv.w);
    }
    fo[b * 1000 + o] = (float)(-s);
}

// ---------------- final BN over batch of 2 ----------------
__global__ __launch_bounds__(256) void final_bn(
    const float* __restrict__ fo, const float* __restrict__ gl, const float* __restrict__ bl,
    float* __restrict__ out)
{
    int o = blockIdx.x * 256 + threadIdx.x;
    if (o >= 1000) return;
    float v0 = fo[o], v1 = fo[1000 + o];
    float mu = 0.5f * (v0 + v1);
    float d = v0 - mu;
    float var = d * d;           // mean of squared deviations for n=2
    float iv = rsqrtf(var + (float)BN_EPS);
    float sg = iv * gl[o];
    out[o] = d * sg + bl[o];
    out[1000 + o] = -d * sg + bl[o];
}

extern "C" void kernel_launch(void* const* d_in, const int* in_sizes, int n_in,
                              void* d_out, int out_size, void* d_ws, size_t ws_size,
                              hipStream_t stream)
{
    const float* x = (const float*)d_in[0];
    const float* Wt[8]; const float* Gt[8]; const float* Bt[8];
    for (int i = 0; i < 8; i++) {
        Wt[i] = (const float*)d_in[1 + 3 * i];
        Gt[i] = (const float*)d_in[2 + 3 * i];
        Bt[i] = (const float*)d_in[3 + 3 * i];
    }
    const float* wl = (const float*)d_in[25];
    const float* gl = (const float*)d_in[26];
    const float* bl = (const float*)d_in[27];
    float* out = (float*)d_out;
    float* ws = (float*)d_ws;

    float* T     = ws;               // 1,179,648 floats (max pre-BN tensor, layer 1)
    float* A     = ws + 1179648;     //   294,912 floats (max next-layer input)
    float* scale = ws + 1474560;     //       512
    float* shift = ws + 1475072;     //       512
    float* xp    = ws + 1475584;     //      1024
    float* fo    = ws + 1476608;     //      2000

    hipMemsetAsync(T, 0, (size_t)1179648 * 4, stream);   // bn_apply re-zeroes for later layers

    static const int Cc[8]  = {3, 64, 128, 256, 256, 512, 512, 512};
    static const int Oc[8]  = {64, 128, 256, 256, 512, 512, 512, 512};
    static const int Hc[8]  = {96, 48, 24, 24, 12, 12, 6, 6};
    static const int RSc[8] = {1, 4, 8, 8, 16, 16, 32, 32};   // split-K -> >=256 blocks/layer
    static const int PLc[8] = {1, 1, 0, 1, 0, 1, 0, 1};
    static const size_t foff[8] = {2000, 1181648, 1771472, 2066384,
                                   2361296, 2508752, 2656208, 2693072};

    const float* cur = x;
    for (int i = 0; i < 8; i++) {
        const int C = Cc[i], O = Oc[i], H = Hc[i], Wd = Hc[i];
        const int TP = (Wd == 6) ? 3 : 4;
        const int tpr = Wd / TP;
        const int PTt = 2 * H * tpr;
        dim3 grid((PTt + 15) / 16, (O + 127) / 128, RSc[i]);
        const int cpr = C / RSc[i];
        if (TP == 4)
            adder_partial<4><<<grid, 256, 0, stream>>>(cur, Wt[i], T, C, H, Wd, O, cpr);
        else
            adder_partial<3><<<grid, 256, 0, stream>>>(cur, Wt[i], T, C, H, Wd, O, cpr);
        const int HW = H * Wd;
        bn_stats<<<O, 256, 0, stream>>>(T, Gt[i], Bt[i], scale, shift, O, HW);
        float* feat = out + foff[i];
        if (PLc[i]) {
            int total = 2 * O * (H / 2) * (Wd / 2);
            bn_apply_pool<<<(total + 255) / 256, 256, 0, stream>>>(T, scale, shift, feat, A, O, H, Wd, total);
        } else {
            int total = 2 * O * HW;
            bn_apply_np<<<(total + 255) / 256, 256, 0, stream>>>(T, scale, shift, feat, A, O, HW, total);
        }
        cur = A;
    }
    gmax9<<<4, 256, 0, stream>>>(A, xp);          // A = (2,512,3,3) after layer-8 pool+relu
    final_adder<<<8, 256, 0, stream>>>(xp, wl, fo);
    final_bn<<<4, 256, 0, stream>>>(fo, gl, bl, out);
}